// Round 7
// baseline (394.076 us; speedup 1.0000x reference)
//
#include <hip/hip_runtime.h>
#include <hip/hip_bf16.h>
#include <math.h>
#include <stdint.h>

// Problem constants: BS=16, SEQ=1024, NV=512, DM=256, K=8
#define BS 16
#define SEQ 1024
#define NV 512
#define DM 256
#define NK 8

typedef float f32x2 __attribute__((ext_vector_type(2)));

// ---------------------------------------------------------------------------
// Module-global scratch. Every launch fully overwrites before reading
// (stream-ordered producer->consumer), so graph replay is self-contained.
// ---------------------------------------------------------------------------
__device__ double g_WC[NK * SEQ];                          // 64 KB
__device__ double g_Bk[NK];                                // 64 B
__device__ __align__(16) float g_Wt[SEQ * DM];             // 1 MB  [s][d]
__device__ __align__(16) float g_zp[4 * BS * NV * DM];     // 33.5 MB [kblk][b][v][d]
__device__ double g_nn2[BS * NV];                          // 64 KB
__device__ double g_Dp[8 * BS * NV * NK];                  // 4 MB [sc][b][v][k]
__device__ unsigned char g_bits[BS * NV];                  // 8 KB

// ---------------------------------------------------------------------------
// Exact JAX threefry2x32 (20 rounds), key = PRNGKey(7) = (0, 7).
// ---------------------------------------------------------------------------
__device__ __forceinline__ void threefry2x32_key7(uint32_t x0, uint32_t x1,
                                                  uint32_t& o0, uint32_t& o1) {
    const uint32_t k0 = 0u, k1 = 7u;
    const uint32_t k2 = k0 ^ k1 ^ 0x1BD11BDAu;
    uint32_t v0 = x0 + k0, v1 = x1 + k1;
#define TF_ROUND(r) { v0 += v1; v1 = (v1 << (r)) | (v1 >> (32 - (r))); v1 ^= v0; }
    TF_ROUND(13) TF_ROUND(15) TF_ROUND(26) TF_ROUND(6)
    v0 += k1; v1 += k2 + 1u;
    TF_ROUND(17) TF_ROUND(29) TF_ROUND(16) TF_ROUND(24)
    v0 += k2; v1 += k0 + 2u;
    TF_ROUND(13) TF_ROUND(15) TF_ROUND(26) TF_ROUND(6)
    v0 += k0; v1 += k1 + 3u;
    TF_ROUND(17) TF_ROUND(29) TF_ROUND(16) TF_ROUND(24)
    v0 += k1; v1 += k2 + 4u;
    TF_ROUND(13) TF_ROUND(15) TF_ROUND(26) TF_ROUND(6)
    v0 += k2; v1 += k0 + 5u;
#undef TF_ROUND
    o0 = v0; o1 = v1;
}

__device__ __forceinline__ float bits_to_uniform(uint32_t b) {
    return __uint_as_float((b >> 9) | 0x3F800000u) - 1.0f;
}

// ---------------------------------------------------------------------------
// Merged prep: blocks 0..31  = WC/Bk prep (8 k x 4 s-chunks),
//              blocks 32..63 = W transpose (16 sblk x 2 dblk).
// ---------------------------------------------------------------------------
__global__ __launch_bounds__(256) void wtprep_kernel(
        const float* __restrict__ W, const float* __restrict__ bias,
        const float* __restrict__ ce) {
    __shared__ __align__(16) char smem[34816];
    const int t = threadIdx.x;

    if (blockIdx.x < 32) {
        double* red = (double*)smem;             // [256]
        double* cen = (double*)(smem + 2048);    // [256]
        const int k = blockIdx.x >> 2;
        const int schunk = blockIdx.x & 3;

        double c = (double)ce[k * DM + t];
        red[t] = c * c;
        __syncthreads();
        for (int off = 128; off > 0; off >>= 1) {
            if (t < off) red[t] += red[t + off];
            __syncthreads();
        }
        double nc = fmax(sqrt(red[0]), 1e-12);
        cen[t] = c / nc;
        __syncthreads();
        red[t] = (double)bias[t] * cen[t];
        __syncthreads();
        for (int off = 128; off > 0; off >>= 1) {
            if (t < off) red[t] += red[t + off];
            __syncthreads();
        }
        if (t == 0 && schunk == 0) g_Bk[k] = red[0];

        const int s = schunk * 256 + t;
        double acc = 0.0;
        for (int d = 0; d < DM; ++d)
            acc += cen[d] * (double)W[(size_t)d * SEQ + s];
        g_WC[(size_t)k * SEQ + s] = acc;
    } else {
        float* tile = (float*)smem;              // [64][132]
        const int bx = blockIdx.x - 32;
        const int s0 = (bx & 15) * 64;
        const int d0 = (bx >> 4) * 128;
#pragma unroll
        for (int p = 0; p < 32; ++p) {
            int lin = p * 256 + t;
            int d = lin >> 6, s = lin & 63;      // read coalesced over s
            tile[s * 132 + d] = W[(size_t)(d0 + d) * SEQ + s0 + s];
        }
        __syncthreads();
#pragma unroll
        for (int p = 0; p < 32; ++p) {
            int lin = p * 256 + t;
            int s = lin >> 7, d = lin & 127;     // write coalesced over d
            g_Wt[(size_t)(s0 + s) * DM + d0 + d] = tile[s * 132 + d];
        }
    }
}

// ---------------------------------------------------------------------------
// GEMM: block tile 128v x 256d, 256 threads, thread tile 8v x 16d held as
// f32x2 acc pairs, inner loop = v_pk_fma_f32 (2 fp32 FMA / VALU inst -> the
// 157 TF packed-fp32 path; scalar v_fmac caps at 78.6 TF). Accumulation
// order per element unchanged vs round 6 -> bitwise-identical z partials.
// kblk=4 K-split (256 s each), grid (4,4,16) = 256 blocks.
// ---------------------------------------------------------------------------
#define KC 32
#define XS_LD 132           // 128 + 4
#define WST_LD 320          // 16 groups x (16 + 4 pad)

__global__ __launch_bounds__(256, 1) void gemm_kernel(
        const float* __restrict__ x) {
    __shared__ __align__(16) float xs[KC * XS_LD];    // 16.9 KB
    __shared__ __align__(16) float wst[KC * WST_LD];  // 40 KB

    const int t = threadIdx.x;
    const int kblk = blockIdx.x;    // 0..3
    const int vblk = blockIdx.y;    // 0..3
    const int b    = blockIdx.z;    // 0..15
    const int v0 = vblk * 128;
    const float* xb = x + (size_t)b * SEQ * NV;

    const int tv8  = (t & 15) * 8;       // v offset (8 rows)
    const int grp  = t >> 4;             // 0..15 -> d group of 16
    const int td16 = grp * 16;           // d offset
    const int wofs = grp * 20;           // padded LDS offset of the group

    f32x2 acc[8][8];                     // [v][d-pair] = 128 VGPRs
#pragma unroll
    for (int j = 0; j < 8; ++j)
#pragma unroll
        for (int i = 0; i < 8; ++i) acc[j][i] = (f32x2){0.0f, 0.0f};

    const int sbeg = kblk * 256;
    for (int s0 = sbeg; s0 < sbeg + 256; s0 += KC) {
        __syncthreads();
        // stage x: 32 s x 128 v, 4 float4 passes
#pragma unroll
        for (int j = 0; j < 4; ++j) {
            int lin = j * 256 + t;
            int sl = lin >> 5, c4 = (lin & 31) << 2;
            float4 val = *(const float4*)&xb[(size_t)(s0 + sl) * NV + v0 + c4];
            *(float4*)&xs[sl * XS_LD + c4] = val;
        }
        // stage Wt: 32 s x 256 d, 8 float4 passes, group-padded store
#pragma unroll
        for (int j = 0; j < 8; ++j) {
            int lin = j * 256 + t;
            int sl = lin >> 6, c4 = (lin & 63) << 2;        // d = c4
            float4 val = *(const float4*)&g_Wt[(size_t)(s0 + sl) * DM + c4];
            *(float4*)&wst[sl * WST_LD + (c4 >> 4) * 20 + (c4 & 15)] = val;
        }
        __syncthreads();
#pragma unroll
        for (int kk = 0; kk < KC; ++kk) {
            const float* xr = &xs[kk * XS_LD + tv8];
            const float* wr = &wst[kk * WST_LD + wofs];
            float4 xv0 = *(const float4*)(xr);
            float4 xv1 = *(const float4*)(xr + 4);
            float4 wv0 = *(const float4*)(wr);
            float4 wv1 = *(const float4*)(wr + 4);
            float4 wv2 = *(const float4*)(wr + 8);
            float4 wv3 = *(const float4*)(wr + 12);
            float xv[8] = {xv0.x, xv0.y, xv0.z, xv0.w, xv1.x, xv1.y, xv1.z, xv1.w};
            f32x2 wp[8] = {{wv0.x, wv0.y}, {wv0.z, wv0.w},
                           {wv1.x, wv1.y}, {wv1.z, wv1.w},
                           {wv2.x, wv2.y}, {wv2.z, wv2.w},
                           {wv3.x, wv3.y}, {wv3.z, wv3.w}};
#pragma unroll
            for (int j = 0; j < 8; ++j) {
                f32x2 xd = {xv[j], xv[j]};
#pragma unroll
                for (int i = 0; i < 8; ++i)
                    asm("v_pk_fma_f32 %0, %1, %2, %0"
                        : "+v"(acc[j][i]) : "v"(xd), "v"(wp[i]));
            }
        }
    }

    // Epilogue: store fp32 z-partials for this kblk.
#pragma unroll
    for (int j = 0; j < 8; ++j) {
        size_t base = (size_t)kblk * (BS * NV * DM) +
                      ((size_t)b * NV + v0 + tv8 + j) * DM + td16;
#pragma unroll
        for (int m = 0; m < 4; ++m)
            *(float4*)&g_zp[base + 4 * m] =
                make_float4(acc[j][2 * m].x, acc[j][2 * m].y,
                            acc[j][2 * m + 1].x, acc[j][2 * m + 1].y);
    }
}

// ---------------------------------------------------------------------------
// Combine: z[b,v,d] = fp64 sum of 4 kblk partials + bias[d]; nn2 = sum_d z^2.
// Grid (vg 32, b 16) = 512 blocks, 256 thr = 16 v x 16 d-groups of 16.
// ---------------------------------------------------------------------------
__global__ __launch_bounds__(256) void combine_kernel(
        const float* __restrict__ bias) {
    __shared__ double red[16][17];
    const int t = threadIdx.x;
    const int vg = blockIdx.x;   // 0..31
    const int b  = blockIdx.y;   // 0..15
    const int vl = t >> 4, dg = t & 15;
    const int v = vg * 16 + vl;

    const size_t bvbase = ((size_t)b * NV + v) * DM + dg * 16;
    double sq = 0.0;
#pragma unroll
    for (int m = 0; m < 16; m += 4) {
        float4 p0 = *(const float4*)&g_zp[(size_t)0 * (BS * NV * DM) + bvbase + m];
        float4 p1 = *(const float4*)&g_zp[(size_t)1 * (BS * NV * DM) + bvbase + m];
        float4 p2 = *(const float4*)&g_zp[(size_t)2 * (BS * NV * DM) + bvbase + m];
        float4 p3 = *(const float4*)&g_zp[(size_t)3 * (BS * NV * DM) + bvbase + m];
        float4 bb = *(const float4*)&bias[dg * 16 + m];
        double z0 = (double)p0.x + (double)p1.x + (double)p2.x + (double)p3.x + (double)bb.x;
        double z1 = (double)p0.y + (double)p1.y + (double)p2.y + (double)p3.y + (double)bb.y;
        double z2 = (double)p0.z + (double)p1.z + (double)p2.z + (double)p3.z + (double)bb.z;
        double z3 = (double)p0.w + (double)p1.w + (double)p2.w + (double)p3.w + (double)bb.w;
        sq += z0 * z0 + z1 * z1 + z2 * z2 + z3 * z3;
    }
    red[vl][dg] = sq;
    __syncthreads();
    if (dg == 0) {
        double s = 0.0;
#pragma unroll
        for (int i = 0; i < 16; ++i) s += red[vl][i];
        g_nn2[b * NV + v] = s;
    }
}

// ---------------------------------------------------------------------------
// D-kernel (unchanged): D_k partials over 128-s chunks, fp64.
// Grid: (vblk=8, b=16, sc=8) = 1024 blocks.
// ---------------------------------------------------------------------------
__global__ __launch_bounds__(256) void dkern(const float* __restrict__ x) {
    __shared__ double wcd[NK][128];
    __shared__ double dw[4][64][NK];
    const int t = threadIdx.x;
    const int vblk = blockIdx.x;
    const int b    = blockIdx.y;
    const int sc   = blockIdx.z;
    const int v0 = vblk * 64;
    const int ss = sc * 128;

#pragma unroll
    for (int j = 0; j < 4; ++j) {
        int idx = j * 256 + t;
        ((double*)wcd)[idx] = g_WC[(size_t)(idx >> 7) * SEQ + ss + (idx & 127)];
    }
    __syncthreads();

    const int vl = t & 63, w = t >> 6;
    const float* xp = x + (size_t)b * SEQ * NV + v0 + vl;
    double D[NK];
#pragma unroll
    for (int k = 0; k < NK; ++k) D[k] = 0.0;
    const int sw = w * 32;
    for (int i = 0; i < 32; ++i) {
        int sl = sw + i;
        double xv = (double)xp[(size_t)(ss + sl) * NV];
#pragma unroll
        for (int k = 0; k < NK; ++k) D[k] += xv * wcd[k][sl];
    }
#pragma unroll
    for (int k = 0; k < NK; ++k) dw[w][vl][k] = D[k];
    __syncthreads();

    const int v = t & 63, k2 = (t >> 6) * 2;
#pragma unroll
    for (int j = 0; j < 2; ++j) {
        int k = k2 + j;
        double s = dw[0][v][k] + dw[1][v][k] + dw[2][v][k] + dw[3][v][k];
        g_Dp[(((size_t)sc * BS + b) * NV + v0 + v) * NK + k] = s;
    }
}

// ---------------------------------------------------------------------------
// Finalize (unchanged): sinkhorn softmax fp64, partitionable threefry, bits.
// ---------------------------------------------------------------------------
__global__ __launch_bounds__(256) void finalize_kernel() {
    const int bv = blockIdx.x * 256 + threadIdx.x;   // 0..8191
    double n = fmax(sqrt(g_nn2[bv]), 1e-12);

    double D[NK];
#pragma unroll
    for (int k = 0; k < NK; ++k) D[k] = g_Bk[k];
#pragma unroll
    for (int sc = 0; sc < 8; ++sc) {
#pragma unroll
        for (int k = 0; k < NK; ++k)
            D[k] += g_Dp[((size_t)sc * (BS * NV) + bv) * NK + k];
    }

    double p[NK], sum = 0.0;
#pragma unroll
    for (int k = 0; k < NK; ++k) {
        p[k] = exp((D[k] / n) / 0.05);
        sum += p[k];
    }
    unsigned int byte = 0;
#pragma unroll
    for (int k = 0; k < NK; ++k) {
        uint32_t i = (uint32_t)(k * (BS * NV) + bv);
        uint32_t y0, y1;
        threefry2x32_key7(0u, i, y0, y1);
        float u = bits_to_uniform(y0 ^ y1);
        if ((double)u < p[k] / sum) byte |= 1u << k;
    }
    g_bits[bv] = (unsigned char)byte;
}

// ---------------------------------------------------------------------------
// Write (unchanged): 268 MB broadcast, float4 stores — at HBM floor.
// ---------------------------------------------------------------------------
__global__ __launch_bounds__(256) void write_kernel(float* __restrict__ out) {
    const int t = threadIdx.x;
    const size_t r0 = (size_t)blockIdx.x * 8;
#pragma unroll
    for (int j = 0; j < 8; ++j) {
        size_t r = r0 + j;                      // r = (k*16+b)*512+v
        unsigned int bv = (unsigned int)(r & 8191u);
        unsigned int k  = (unsigned int)(r >> 13);
        float v = ((g_bits[bv] >> k) & 1u) ? 1.0f : 0.0f;
        float4 val = make_float4(v, v, v, v);
        ((float4*)(out + r * 1024))[t] = val;
    }
}

// ---------------------------------------------------------------------------
extern "C" void kernel_launch(void* const* d_in, const int* in_sizes, int n_in,
                              void* d_out, int out_size, void* d_ws, size_t ws_size,
                              hipStream_t stream) {
    const float* x    = (const float*)d_in[0];
    const float* W    = (const float*)d_in[1];
    const float* bias = (const float*)d_in[2];
    const float* ce   = (const float*)d_in[3];
    float* out = (float*)d_out;

    wtprep_kernel<<<dim3(64), dim3(256), 0, stream>>>(W, bias, ce);
    gemm_kernel<<<dim3(4, 4, 16), dim3(256), 0, stream>>>(x);
    combine_kernel<<<dim3(32, 16), dim3(256), 0, stream>>>(bias);
    dkern<<<dim3(8, 16, 8), dim3(256), 0, stream>>>(x);
    finalize_kernel<<<dim3(32), dim3(256), 0, stream>>>();
    write_kernel<<<dim3(8192), dim3(256), 0, stream>>>(out);
}